// Round 2
// baseline (409.432 us; speedup 1.0000x reference)
//
#include <hip/hip_runtime.h>
#include <math.h>

#define B_    64
#define KP1   16385      // K+1
#define D_    128
#define N_    500000
#define INV_T (1.0f / 0.07f)
#define MOM_  0.5f

#define TOTAL_BLOCKS 2048          // 256 CU x 8 blocks (256 thr) = fully resident
#define COPY_BLOCKS  768           // ~40% of traffic is the streaming copy
#define SCORE_BLOCKS (TOTAL_BLOCKS - COPY_BLOCKS)

// Fused: block-specialized persistent kernel.
//   blocks [0, COPY_BLOCKS)        : stream-copy mem_l, mem_ab -> out banks
//   blocks [COPY_BLOCKS, TOTAL)    : gather rows + dot + /T -> scores
__global__ __launch_bounds__(256)
void fused_kernel(const float* __restrict__ l,
                  const float* __restrict__ ab,
                  const float* __restrict__ mem_l,
                  const float* __restrict__ mem_ab,
                  const int* __restrict__ idx,
                  float* __restrict__ out,         // scores: [2 * B * KP1]
                  float* __restrict__ out_mem_l) { // banks: contiguous 2*N*D floats
    if (blockIdx.x < COPY_BLOCKS) {
        const int half = COPY_BLOCKS / 2;
        const int cb   = blockIdx.x;
        const size_t NE4 = (size_t)N_ * D_ / 4;     // float4 per bank
        const float4* src;
        float4* dst;
        int blk0;
        if (cb < half) {
            src = (const float4*)mem_l;  dst = (float4*)out_mem_l;        blk0 = 0;
        } else {
            src = (const float4*)mem_ab; dst = (float4*)out_mem_l + NE4;  blk0 = half;
        }
        const size_t nthreads = (size_t)half * 256;
        for (size_t i = (size_t)(cb - blk0) * 256 + threadIdx.x; i < NE4; i += nthreads)
            dst[i] = src[i];
    } else {
        const int group = threadIdx.x >> 5;          // 8 groups of 32 lanes
        const int glane = threadIdx.x & 31;
        const size_t BK = (size_t)B_ * KP1;
        const unsigned gid     = (blockIdx.x - COPY_BLOCKS) * 8u + group;
        const unsigned ngroups = SCORE_BLOCKS * 8u;  // even -> bank constant/group
        const unsigned total   = 2u * (unsigned)BK;

        for (unsigned t = gid; t < total; t += ngroups) {
            const unsigned bank = t & 1u;            // 0: mem_ab . l -> out_l
            const unsigned kk   = t >> 1;            // flat b*KP1+k
            const unsigned b    = kk / KP1;          // magic-mul div by const
            const int ridx = idx[kk];

            const float4 r = ((const float4*)((bank ? mem_l : mem_ab)
                                              + (size_t)ridx * D_))[glane];
            const float4 f = ((const float4*)((bank ? ab : l)
                                              + (size_t)b * D_))[glane];
            float v = r.x * f.x + r.y * f.y + r.z * f.z + r.w * f.w;
            #pragma unroll
            for (int m = 16; m >= 1; m >>= 1) v += __shfl_xor(v, m);

            if (glane == 0)
                out[(size_t)bank * BK + kk] = v * INV_T;
        }
    }
}

// One block per b; wave 0 updates memory_l row, wave 1 updates memory_ab row.
// Runs AFTER fused_kernel (stream order) so it overwrites the copied rows.
__global__ __launch_bounds__(128)
void ema_update_kernel(const float* __restrict__ l,
                       const float* __restrict__ ab,
                       const float* __restrict__ mem_l,
                       const float* __restrict__ mem_ab,
                       const int* __restrict__ y,
                       float* __restrict__ out_mem_l,
                       float* __restrict__ out_mem_ab) {
    const int b    = blockIdx.x;
    const int wave = threadIdx.x >> 6;
    const int lane = threadIdx.x & 63;
    const int yb   = y[b];

    const float* mem  = wave ? mem_ab     : mem_l;
    const float* feat = wave ? ab         : l;
    float*       om   = wave ? out_mem_ab : out_mem_l;

    const float2 m2 = ((const float2*)(mem  + (size_t)yb * D_))[lane];
    const float2 f2 = ((const float2*)(feat + (size_t)b  * D_))[lane];

    float px = m2.x * MOM_ + f2.x * (1.0f - MOM_);
    float py = m2.y * MOM_ + f2.y * (1.0f - MOM_);
    float ss = px * px + py * py;
    #pragma unroll
    for (int m = 32; m >= 1; m >>= 1) ss += __shfl_xor(ss, m);
    const float rn = 1.0f / sqrtf(ss);

    ((float2*)(om + (size_t)yb * D_))[lane] = make_float2(px * rn, py * rn);
}

extern "C" void kernel_launch(void* const* d_in, const int* in_sizes, int n_in,
                              void* d_out, int out_size, void* d_ws, size_t ws_size,
                              hipStream_t stream) {
    const float* l      = (const float*)d_in[0];
    const float* ab     = (const float*)d_in[1];
    const float* mem_l  = (const float*)d_in[2];
    const float* mem_ab = (const float*)d_in[3];
    const int*   y      = (const int*)d_in[4];
    const int*   idx    = (const int*)d_in[5];
    float* out = (float*)d_out;

    const size_t BK = (size_t)B_ * KP1;
    float* out_mem_l  = out + 2 * BK;
    float* out_mem_ab = out_mem_l + (size_t)N_ * D_;

    fused_kernel<<<TOTAL_BLOCKS, 256, 0, stream>>>(l, ab, mem_l, mem_ab, idx,
                                                   out, out_mem_l);
    ema_update_kernel<<<B_, 128, 0, stream>>>(l, ab, mem_l, mem_ab, y,
                                              out_mem_l, out_mem_ab);
}

// Round 3
// 360.064 us; speedup vs baseline: 1.1371x; 1.1371x over previous
//
#include <hip/hip_runtime.h>
#include <math.h>

#define B_    64
#define KP1   16385      // K+1
#define D_    128
#define N_    500000
#define INV_T (1.0f / 0.07f)
#define MOM_  0.5f

#define TOTAL_BLOCKS 2048
#define COPY_BLOCKS  1024
#define SCORE_BLOCKS (TOTAL_BLOCKS - COPY_BLOCKS)
#define NGROUPS      (SCORE_BLOCKS * 8)        // 32-lane groups on score side
#define GROUPS_PER_PAIR (NGROUPS / (2 * B_))   // 8192/128 = 64
#define CHUNK        ((KP1 + GROUPS_PER_PAIR - 1) / GROUPS_PER_PAIR)  // 257

// Fused block-specialized kernel:
//   blocks [0, COPY_BLOCKS)     : stream-copy mem_l, mem_ab -> out banks
//   blocks [COPY_BLOCKS, TOTAL) : gather rows + dot + /T -> scores
// Score mapping: group -> fixed (b, bank), contiguous k-chunk.
//   Feature vec in registers; k-loop unrolled x4 -> 4 independent row loads
//   in flight per group (latency -> BW bound).
__global__ __launch_bounds__(256)
void fused_kernel(const float* __restrict__ l,
                  const float* __restrict__ ab,
                  const float* __restrict__ mem_l,
                  const float* __restrict__ mem_ab,
                  const int* __restrict__ idx,
                  float* __restrict__ out,          // scores: [2 * B * KP1]
                  float* __restrict__ out_mem_l) {  // banks: 2*N*D floats contiguous
    if (blockIdx.x < COPY_BLOCKS) {
        const int half = COPY_BLOCKS / 2;
        const int cb   = blockIdx.x;
        const size_t NE4 = (size_t)N_ * D_ / 4;
        const float4* src;
        float4* dst;
        int blk0;
        if (cb < half) {
            src = (const float4*)mem_l;  dst = (float4*)out_mem_l;        blk0 = 0;
        } else {
            src = (const float4*)mem_ab; dst = (float4*)out_mem_l + NE4;  blk0 = half;
        }
        const size_t nthreads = (size_t)half * 256;
        for (size_t i = (size_t)(cb - blk0) * 256 + threadIdx.x; i < NE4; i += nthreads)
            dst[i] = src[i];
    } else {
        const int group = threadIdx.x >> 5;
        const int glane = threadIdx.x & 31;
        const unsigned gid = (blockIdx.x - COPY_BLOCKS) * 8u + group;

        const unsigned pair  = gid & (2u * B_ - 1u);  // 128 pairs (pow2)
        const unsigned gslot = gid >> 7;              // [0, GROUPS_PER_PAIR)
        const unsigned bank  = pair & 1u;
        const unsigned b     = pair >> 1;

        const int k0   = (int)(gslot * CHUNK);
        const int kend = min(k0 + CHUNK, KP1);

        const float* mem  = bank ? mem_l : mem_ab;
        const float* feat = bank ? ab    : l;
        const float4 f4 = ((const float4*)(feat + (size_t)b * D_))[glane];

        const int* idxb = idx + (size_t)b * KP1;
        const size_t BK = (size_t)B_ * KP1;
        float* outb = out + (size_t)bank * BK + (size_t)b * KP1;

        int k = k0;
        for (; k + 3 < kend; k += 4) {
            const int i0 = idxb[k], i1 = idxb[k + 1], i2 = idxb[k + 2], i3 = idxb[k + 3];
            const float4 r0 = ((const float4*)(mem + (size_t)i0 * D_))[glane];
            const float4 r1 = ((const float4*)(mem + (size_t)i1 * D_))[glane];
            const float4 r2 = ((const float4*)(mem + (size_t)i2 * D_))[glane];
            const float4 r3 = ((const float4*)(mem + (size_t)i3 * D_))[glane];

            float v0 = r0.x * f4.x + r0.y * f4.y + r0.z * f4.z + r0.w * f4.w;
            float v1 = r1.x * f4.x + r1.y * f4.y + r1.z * f4.z + r1.w * f4.w;
            float v2 = r2.x * f4.x + r2.y * f4.y + r2.z * f4.z + r2.w * f4.w;
            float v3 = r3.x * f4.x + r3.y * f4.y + r3.z * f4.z + r3.w * f4.w;

            #pragma unroll
            for (int m = 16; m >= 1; m >>= 1) {
                v0 += __shfl_xor(v0, m);
                v1 += __shfl_xor(v1, m);
                v2 += __shfl_xor(v2, m);
                v3 += __shfl_xor(v3, m);
            }

            // lane j (<4) stores item j -> one 16B-wide coalesced burst
            float vv = glane == 1 ? v1 : glane == 2 ? v2 : glane == 3 ? v3 : v0;
            if (glane < 4) outb[k + glane] = vv * INV_T;
        }
        for (; k < kend; ++k) {
            const int i0 = idxb[k];
            const float4 r0 = ((const float4*)(mem + (size_t)i0 * D_))[glane];
            float v0 = r0.x * f4.x + r0.y * f4.y + r0.z * f4.z + r0.w * f4.w;
            #pragma unroll
            for (int m = 16; m >= 1; m >>= 1) v0 += __shfl_xor(v0, m);
            if (glane == 0) outb[k] = v0 * INV_T;
        }
    }
}

// One block per b; wave 0 updates memory_l row, wave 1 updates memory_ab row.
// Runs AFTER fused_kernel (stream order) so it overwrites the copied rows.
__global__ __launch_bounds__(128)
void ema_update_kernel(const float* __restrict__ l,
                       const float* __restrict__ ab,
                       const float* __restrict__ mem_l,
                       const float* __restrict__ mem_ab,
                       const int* __restrict__ y,
                       float* __restrict__ out_mem_l,
                       float* __restrict__ out_mem_ab) {
    const int b    = blockIdx.x;
    const int wave = threadIdx.x >> 6;
    const int lane = threadIdx.x & 63;
    const int yb   = y[b];

    const float* mem  = wave ? mem_ab     : mem_l;
    const float* feat = wave ? ab         : l;
    float*       om   = wave ? out_mem_ab : out_mem_l;

    const float2 m2 = ((const float2*)(mem  + (size_t)yb * D_))[lane];
    const float2 f2 = ((const float2*)(feat + (size_t)b  * D_))[lane];

    float px = m2.x * MOM_ + f2.x * (1.0f - MOM_);
    float py = m2.y * MOM_ + f2.y * (1.0f - MOM_);
    float ss = px * px + py * py;
    #pragma unroll
    for (int m = 32; m >= 1; m >>= 1) ss += __shfl_xor(ss, m);
    const float rn = 1.0f / sqrtf(ss);

    ((float2*)(om + (size_t)yb * D_))[lane] = make_float2(px * rn, py * rn);
}

extern "C" void kernel_launch(void* const* d_in, const int* in_sizes, int n_in,
                              void* d_out, int out_size, void* d_ws, size_t ws_size,
                              hipStream_t stream) {
    const float* l      = (const float*)d_in[0];
    const float* ab     = (const float*)d_in[1];
    const float* mem_l  = (const float*)d_in[2];
    const float* mem_ab = (const float*)d_in[3];
    const int*   y      = (const int*)d_in[4];
    const int*   idx    = (const int*)d_in[5];
    float* out = (float*)d_out;

    const size_t BK = (size_t)B_ * KP1;
    float* out_mem_l  = out + 2 * BK;
    float* out_mem_ab = out_mem_l + (size_t)N_ * D_;

    fused_kernel<<<TOTAL_BLOCKS, 256, 0, stream>>>(l, ab, mem_l, mem_ab, idx,
                                                   out, out_mem_l);
    ema_update_kernel<<<B_, 128, 0, stream>>>(l, ab, mem_l, mem_ab, y,
                                              out_mem_l, out_mem_ab);
}

// Round 4
// 327.802 us; speedup vs baseline: 1.2490x; 1.0984x over previous
//
#include <hip/hip_runtime.h>
#include <math.h>

#define B_    64
#define KP1   16385                // K+1
#define D_    128
#define N_    500000
#define INV_T (1.0f / 0.07f)
#define MOM_  0.5f

#define NBLK   2048
#define NTHR   (NBLK * 256)        // 524288 threads
#define NGRP   (NBLK * 8)          // 16384 32-lane groups
#define BK_    (B_ * KP1)          // 1048640 items per bank
#define TOT_   (2 * BK_)           // 2097280 score items (flat out index!)
#define NE4B   (N_ * D_ / 4)       // 16,000,000 float4 per bank
#define CPITER 31                  // ceil(NE4B / NTHR)
#define BASEQ  32                  // score quads per group (main)
#define REMG   32                  // first REMG groups take one extra quad

__device__ __forceinline__ float dot4(const float4 r, const float4 f) {
    return r.x * f.x + r.y * f.y + r.z * f.z + r.w * f.w;
}

__device__ __forceinline__ void score_quad(
        unsigned t, int glane,
        const float* __restrict__ l, const float* __restrict__ ab,
        const float* __restrict__ mem_l, const float* __restrict__ mem_ab,
        const int* __restrict__ idx, float* __restrict__ out) {
    // items t..t+3 ; flat out index == t ; u = t mod BK_ indexes idx
    const unsigned bank0 = (t >= (unsigned)BK_) ? 1u : 0u;
    const unsigned u0    = t - bank0 * (unsigned)BK_;
    const unsigned b0    = u0 / KP1;
    const unsigned k0    = u0 - b0 * KP1;

    if (k0 <= (unsigned)(KP1 - 4)) {
        // fast path: all 4 items share (bank, b)
        const float* mem  = bank0 ? mem_l : mem_ab;
        const float* feat = bank0 ? ab    : l;
        const float4 f = ((const float4*)(feat + (size_t)b0 * D_))[glane];

        const int i0 = idx[u0],     i1 = idx[u0 + 1];
        const int i2 = idx[u0 + 2], i3 = idx[u0 + 3];
        const float4 r0 = ((const float4*)(mem + (size_t)i0 * D_))[glane];
        const float4 r1 = ((const float4*)(mem + (size_t)i1 * D_))[glane];
        const float4 r2 = ((const float4*)(mem + (size_t)i2 * D_))[glane];
        const float4 r3 = ((const float4*)(mem + (size_t)i3 * D_))[glane];

        float v0 = dot4(r0, f), v1 = dot4(r1, f);
        float v2 = dot4(r2, f), v3 = dot4(r3, f);
        #pragma unroll
        for (int m = 16; m >= 1; m >>= 1) {
            v0 += __shfl_xor(v0, m);
            v1 += __shfl_xor(v1, m);
            v2 += __shfl_xor(v2, m);
            v3 += __shfl_xor(v3, m);
        }
        float vv = glane == 1 ? v1 : glane == 2 ? v2 : glane == 3 ? v3 : v0;
        if (glane < 4) out[t + glane] = vv * INV_T;
    } else {
        // slow path: quad crosses a b (or bank) boundary
        #pragma unroll
        for (int i = 0; i < 4; ++i) {
            const unsigned ti = t + i;
            const unsigned bk = (ti >= (unsigned)BK_) ? 1u : 0u;
            const unsigned u  = ti - bk * (unsigned)BK_;
            const unsigned b  = u / KP1;
            const float* mem  = bk ? mem_l : mem_ab;
            const float* feat = bk ? ab    : l;
            const float4 f = ((const float4*)(feat + (size_t)b * D_))[glane];
            const int ri = idx[u];
            const float4 r = ((const float4*)(mem + (size_t)ri * D_))[glane];
            float v = dot4(r, f);
            #pragma unroll
            for (int m = 16; m >= 1; m >>= 1) v += __shfl_xor(v, m);
            if (glane == 0) out[ti] = v * INV_T;
        }
    }
}

// Uniform-mixed kernel: every block interleaves streaming bank-copy (per
// thread) with gather-score quads (per 32-lane group) so both traffic types
// coexist on every CU for the whole dispatch.
__global__ __launch_bounds__(256)
void fused_kernel(const float* __restrict__ l,
                  const float* __restrict__ ab,
                  const float* __restrict__ mem_l,
                  const float* __restrict__ mem_ab,
                  const int* __restrict__ idx,
                  float* __restrict__ out,          // scores [TOT_] (flat == t)
                  float* __restrict__ out_mem_l) {  // banks: 2*N*D contiguous
    const unsigned tid   = blockIdx.x * 256u + threadIdx.x;
    const int      glane = threadIdx.x & 31;
    const unsigned g     = (blockIdx.x << 3) + (threadIdx.x >> 5);

    const float4* srcL  = (const float4*)mem_l;
    const float4* srcAB = (const float4*)mem_ab;
    float4* dstL  = (float4*)out_mem_l;
    float4* dstAB = dstL + NE4B;

    for (int j = 0; j < BASEQ; ++j) {
        if (j < CPITER) {
            const size_t e = (size_t)j * NTHR + tid;
            if (e < (size_t)NE4B) {
                dstL[e]  = srcL[e];
                dstAB[e] = srcAB[e];
            }
        }
        score_quad(4u * (g + (unsigned)j * NGRP), glane,
                   l, ab, mem_l, mem_ab, idx, out);
    }
    if (g < REMG)
        score_quad(4u * ((unsigned)BASEQ * NGRP + g), glane,
                   l, ab, mem_l, mem_ab, idx, out);
}

// One block per b; wave 0 updates memory_l row, wave 1 updates memory_ab row.
// Runs AFTER fused_kernel (stream order) so it overwrites the copied rows.
__global__ __launch_bounds__(128)
void ema_update_kernel(const float* __restrict__ l,
                       const float* __restrict__ ab,
                       const float* __restrict__ mem_l,
                       const float* __restrict__ mem_ab,
                       const int* __restrict__ y,
                       float* __restrict__ out_mem_l,
                       float* __restrict__ out_mem_ab) {
    const int b    = blockIdx.x;
    const int wave = threadIdx.x >> 6;
    const int lane = threadIdx.x & 63;
    const int yb   = y[b];

    const float* mem  = wave ? mem_ab     : mem_l;
    const float* feat = wave ? ab         : l;
    float*       om   = wave ? out_mem_ab : out_mem_l;

    const float2 m2 = ((const float2*)(mem  + (size_t)yb * D_))[lane];
    const float2 f2 = ((const float2*)(feat + (size_t)b  * D_))[lane];

    float px = m2.x * MOM_ + f2.x * (1.0f - MOM_);
    float py = m2.y * MOM_ + f2.y * (1.0f - MOM_);
    float ss = px * px + py * py;
    #pragma unroll
    for (int m = 32; m >= 1; m >>= 1) ss += __shfl_xor(ss, m);
    const float rn = 1.0f / sqrtf(ss);

    ((float2*)(om + (size_t)yb * D_))[lane] = make_float2(px * rn, py * rn);
}

extern "C" void kernel_launch(void* const* d_in, const int* in_sizes, int n_in,
                              void* d_out, int out_size, void* d_ws, size_t ws_size,
                              hipStream_t stream) {
    const float* l      = (const float*)d_in[0];
    const float* ab     = (const float*)d_in[1];
    const float* mem_l  = (const float*)d_in[2];
    const float* mem_ab = (const float*)d_in[3];
    const int*   y      = (const int*)d_in[4];
    const int*   idx    = (const int*)d_in[5];
    float* out = (float*)d_out;

    float* out_mem_l  = out + (size_t)TOT_;
    float* out_mem_ab = out_mem_l + (size_t)N_ * D_;

    fused_kernel<<<NBLK, 256, 0, stream>>>(l, ab, mem_l, mem_ab, idx,
                                           out, out_mem_l);
    ema_update_kernel<<<B_, 128, 0, stream>>>(l, ab, mem_l, mem_ab, y,
                                              out_mem_l, out_mem_ab);
}